// Round 6
// baseline (181.785 us; speedup 1.0000x reference)
//
#include <hip/hip_runtime.h>
#include <math.h>

// ---------------- problem constants ----------------
#define N        2048
#define NT       256      // threads per block
#define NSC      81       // number of scales (J+1)
#define BATCH    64
#define WS_WIN   94       // sliding window = 32*3-2
#define NOUT     1955     // N - WS_WIN + 1
#define DT_S     0.1f
#define W0_C     6.0f
#define PI_F     3.14159265358979f
#define TWOPI_F  6.28318530717959f
#define PIM14    0.7511255444649425f   // pi^(-1/4)
#define C_SQ2H   0.70710678118654752f  // sqrt(2)/2

// XOR-swizzle (size-preserving, bijective on [0,2048)): banks spread without
// padding, so LDS/block = exactly 2x2048x8 = 32768 B -> 4 blocks/CU under the
// ~128 KiB/CU allocatable-LDS cap (34816 B/block capped us at 3 blocks).
// Bank check (b64, pair = e' mod 16): stride-256/512 reads 2-way, m=1/m=64
// writes 2-way (free), m=8 writes 4-way on 8 insts (~1.58x those only).
#define SWZ(e)   ((e) ^ (((e) >> 5) & 31))
#define LDSN     2048

typedef float f4v __attribute__((ext_vector_type(4)));

__device__ __forceinline__ float4 ntload4(const float4* p) {
    f4v t = __builtin_nontemporal_load((const f4v*)p);
    return make_float4(t.x, t.y, t.z, t.w);
}
__device__ __forceinline__ void ntstore4(float4* p, float4 v) {
    f4v t; t.x = v.x; t.y = v.y; t.z = v.z; t.w = v.w;
    __builtin_nontemporal_store(t, (f4v*)p);
}

__device__ __forceinline__ float2 cadd2(float2 a, float2 b) { return make_float2(a.x + b.x, a.y + b.y); }
__device__ __forceinline__ float2 csub2(float2 a, float2 b) { return make_float2(a.x - b.x, a.y - b.y); }
__device__ __forceinline__ float2 cmul2(float2 a, float2 b) { return make_float2(a.x * b.x - a.y * b.y, a.x * b.y + a.y * b.x); }

// ---------------- precomputed twiddles ----------------
// Per thread, the 3 twiddled stages of the 2048-pt FFT use fixed angles:
//   stage1 (m=1):  jm = tid;  stage2 (m=8): jm = tid&~7;  stage3 (m=64): jm = tid&~63
// Store w^1..w^7 at SGN=-1 once; SGN=+1 passes use the conjugate (free).
struct Tw { float2 w[3][7]; };

__device__ __forceinline__ void tw_init(Tw& tw, int tid) {
    const int jms[3] = { tid, tid & ~7, tid & ~63 };
    #pragma unroll
    for (int t = 0; t < 3; ++t) {
        float ang = -(TWOPI_F / (float)N) * (float)jms[t];  // SGN=-1 base
        float sn, cs; __sincosf(ang, &sn, &cs);
        float2 w1 = make_float2(cs, sn);
        tw.w[t][0] = w1;
        #pragma unroll
        for (int p = 1; p < 7; ++p) tw.w[t][p] = cmul2(tw.w[t][p - 1], w1);
    }
}

// multiply by stored twiddle (SGN=-1) or its conjugate (SGN=+1)
template<int SGN>
__device__ __forceinline__ float2 cmul_tw(float2 a, float2 w) {
    if (SGN < 0) return make_float2(a.x * w.x - a.y * w.y, a.x * w.y + a.y * w.x);
    else         return make_float2(a.x * w.x + a.y * w.y, a.y * w.x - a.x * w.y);
}

// 8-point DFT, natural-order outputs (sign SGN).
// HALF=true: x[4..7] are known zero (one-sided spectrum input).
template<int SGN, bool HALF>
__device__ __forceinline__ void dft8(const float2 (&x)[8], float2 (&y)[8]) {
    const float s = (float)SGN;
    float2 t0, t1, t2, t3, u0, d1, d2, d3;
    if (HALF) {
        t0 = x[0]; t1 = x[1]; t2 = x[2]; t3 = x[3];
        u0 = x[0]; d1 = x[1]; d2 = x[2]; d3 = x[3];
    } else {
        t0 = cadd2(x[0], x[4]); t1 = cadd2(x[1], x[5]);
        t2 = cadd2(x[2], x[6]); t3 = cadd2(x[3], x[7]);
        u0 = csub2(x[0], x[4]);
        d1 = csub2(x[1], x[5]);
        d2 = csub2(x[2], x[6]);
        d3 = csub2(x[3], x[7]);
    }
    float2 u1 = make_float2(C_SQ2H * (d1.x - s * d1.y), C_SQ2H * (d1.y + s * d1.x));
    float2 u2 = make_float2(-s * d2.y, s * d2.x);
    float2 u3 = make_float2(-C_SQ2H * (d3.x + s * d3.y), C_SQ2H * (s * d3.x - d3.y));
    float2 a0 = cadd2(t0, t2), a1 = cadd2(t1, t3), b0 = csub2(t0, t2), e1 = csub2(t1, t3);
    float2 b1 = make_float2(-s * e1.y, s * e1.x);
    y[0] = cadd2(a0, a1); y[4] = csub2(a0, a1); y[2] = cadd2(b0, b1); y[6] = csub2(b0, b1);
    float2 c0 = cadd2(u0, u2), c1 = cadd2(u1, u3), g0 = csub2(u0, u2), h1 = csub2(u1, u3);
    float2 g1 = make_float2(-s * h1.y, s * h1.x);
    y[1] = cadd2(c0, c1); y[5] = csub2(c0, c1); y[3] = cadd2(g0, g1); y[7] = csub2(g0, g1);
}

// apply precomputed twiddles and scatter-store
template<int SGN>
__device__ __forceinline__ void twiddle_store(const float2 (&y)[8], float2* __restrict__ dst,
                                              const float2 (&w)[7], int base, int m) {
    dst[SWZ(base)] = y[0];
    #pragma unroll
    for (int p = 1; p < 8; ++p)
        dst[SWZ(base + p * m)] = cmul_tw<SGN>(y[p], w[p - 1]);
}

// stage 1 (m=1): input from registers x[p] = element tid + p*256
template<int SGN, bool HALF>
__device__ __forceinline__ void stage1_reg(const float2 (&x)[8], float2* __restrict__ dst,
                                           const Tw& tw, int tid) {
    float2 y[8];
    dft8<SGN, HALF>(x, y);
    twiddle_store<SGN>(y, dst, tw.w[0], 8 * tid, 1);
}

// split middle stage: read phase (gather 8) -- must be followed by a barrier
// before the in-place write phase
__device__ __forceinline__ void stage_read(const float2* __restrict__ src, float2 (&x)[8], int q) {
    #pragma unroll
    for (int p = 0; p < 8; ++p) x[p] = src[SWZ(q + p * 256)];
}

// split middle stage: dft + twiddle + in-place scatter write. TWS: 1 for m=8, 2 for m=64
template<int SGN, int TWS>
__device__ __forceinline__ void stage_write(float2* __restrict__ dst, const float2 (&x)[8],
                                            const Tw& tw, int q) {
    float2 y[8];
    dft8<SGN, false>(x, y);
    const int m  = (TWS == 1) ? 8 : 64;
    const int jm = q & ~(m - 1);
    twiddle_store<SGN>(y, dst, tw.w[TWS], q + 7 * jm, m);
}

// final radix-4 stage (m=512, j=0, no twiddles): outputs land back in regs,
// x[2u+qq] = element tid + (2u+qq)*256  (natural order, thread-owned)
template<int SGN>
__device__ __forceinline__ void stage4_regs(const float2* __restrict__ src, float2 (&x)[8], int tid) {
    const float s = (float)SGN;
    #pragma unroll
    for (int qq = 0; qq < 2; ++qq) {
        int q = tid + qq * 256;
        float2 x0 = src[SWZ(q)];
        float2 x1 = src[SWZ(q + 512)];
        float2 x2 = src[SWZ(q + 1024)];
        float2 x3 = src[SWZ(q + 1536)];
        float2 a0 = cadd2(x0, x2), a1 = cadd2(x1, x3);
        float2 b0 = csub2(x0, x2), e1 = csub2(x1, x3);
        float2 b1 = make_float2(-s * e1.y, s * e1.x);
        x[0 + qq] = cadd2(a0, a1);
        x[2 + qq] = cadd2(b0, b1);
        x[4 + qq] = csub2(a0, a1);
        x[6 + qq] = csub2(b0, b1);
    }
}

// fused dual-signal 2048-pt FFT, register in / register out.
// In-place per-signal buffers (U, V), read-phase/write-phase split per stage.
// SGN=-1: forward (numpy fft). SGN=+1: inverse exponent (1/N not applied).
// HALF=true: inputs' upper halves (elements k>=1024) are zero.
template<int SGN, bool HALF>
__device__ __forceinline__ void fft2048_dual(float2 (&u)[8], float2 (&v)[8],
                                             float2* U, float2* V, const Tw& tw, int tid) {
    __syncthreads();                        // protect buffers from previous pass's reads
    stage1_reg<SGN, HALF>(u, U, tw, tid);   // regs -> U/V   (m=1)
    stage1_reg<SGN, HALF>(v, V, tw, tid);
    __syncthreads();
    float2 xu[8], xv[8];
    stage_read(U, xu, tid);                 // m=8 read
    stage_read(V, xv, tid);
    __syncthreads();
    stage_write<SGN, 1>(U, xu, tw, tid);    // m=8 write (in place)
    stage_write<SGN, 1>(V, xv, tw, tid);
    __syncthreads();
    stage_read(U, xu, tid);                 // m=64 read
    stage_read(V, xv, tid);
    __syncthreads();
    stage_write<SGN, 2>(U, xu, tw, tid);    // m=64 write (in place)
    stage_write<SGN, 2>(V, xv, tw, tid);
    __syncthreads();
    stage4_regs<SGN>(U, u, tid);            // m=512 -> regs
    stage4_regs<SGN>(V, v, tid);
}

// single-signal variant (k_fft_in), same in-place structure, one buffer
template<int SGN>
__device__ __forceinline__ void fft2048_single(float2 (&u)[8], float2* U, const Tw& tw, int tid) {
    __syncthreads();
    stage1_reg<SGN, false>(u, U, tw, tid);
    __syncthreads();
    float2 x[8];
    stage_read(U, x, tid);
    __syncthreads();
    stage_write<SGN, 1>(U, x, tw, tid);
    __syncthreads();
    stage_read(U, x, tid);
    __syncthreads();
    stage_write<SGN, 2>(U, x, tw, tid);
    __syncthreads();
    stage4_regs<SGN>(U, u, tid);
}

// ---------------- K1: normalize + forward FFT of each signal ----------------
__global__ __launch_bounds__(NT) void k_fft_in(const float* __restrict__ x,
                                               float2* __restrict__ spec) {
    __shared__ float2 A[LDSN];
    __shared__ float rs[4], rq[4];
    const int    tid = threadIdx.x;
    const float* y   = x + (size_t)blockIdx.x * N;

    Tw tw; tw_init(tw, tid);

    float v[8];
    float lsum = 0.f, lsq = 0.f;
    #pragma unroll
    for (int i = 0; i < 8; ++i) {
        float t = y[tid + i * NT];
        v[i] = t; lsum += t; lsq += t * t;
    }
    // wave butterfly reduce, then 4 partials through LDS (1 barrier)
    #pragma unroll
    for (int o = 1; o < 64; o <<= 1) {
        lsum += __shfl_xor(lsum, o, 64);
        lsq  += __shfl_xor(lsq,  o, 64);
    }
    const int wid = tid >> 6, lane = tid & 63;
    if (lane == 0) { rs[wid] = lsum; rq[wid] = lsq; }
    __syncthreads();
    const float fsum = rs[0] + rs[1] + rs[2] + rs[3];
    const float fsq  = rq[0] + rq[1] + rq[2] + rq[3];
    const float mean = fsum * (1.f / N);
    const float var  = fsq * (1.f / N) - mean * mean;
    const float inv  = rsqrtf(var);

    float2 z[8];
    #pragma unroll
    for (int i = 0; i < 8; ++i) z[i] = make_float2((v[i] - mean) * inv, 0.f);

    fft2048_single<-1>(z, A, tw, tid);

    float2* o2 = spec + (size_t)blockIdx.x * N;
    #pragma unroll
    for (int i = 0; i < 8; ++i) o2[tid + i * NT] = z[i];   // spec is hot: keep cached
}

// ---------------- K2: per (batch, scale) CWT + smoothing ----------------
// LDS = 2x2048x8 = 32768 B exactly -> 4 blocks/CU under the ~128 KiB cap.
// VGPR 64 allows 8 waves/SIMD, so LDS remains the binder at 4 blocks (50%).
__global__ __launch_bounds__(NT, 4) void k_wct(const float2* __restrict__ spec,
                                               float4* __restrict__ T, int b0) {
    __shared__ float2 U[LDSN];
    __shared__ float2 V[LDSN];
    const int tid  = threadIdx.x;
    const int sidx = blockIdx.x % NSC;
    const int bl   = blockIdx.x / NSC;
    const int b    = b0 + bl;

    Tw tw; tw_init(tw, tid);

    const float s0    = 2.f * DT_S * (W0_C + sqrtf(2.f + W0_C * W0_C)) / (4.f * PI_F);
    const float s     = s0 * exp2f(0.125f * (float)sidx);
    const float inv_s = 1.f / s;

    const float2* yh1 = spec + (size_t)(b * 2 + 0) * N;
    const float2* yh2 = spec + (size_t)(b * 2 + 1) * N;

    // Morlet filter (w>0 one-sided), unit-energy norm, ifft 1/N folded in.
    // Upper half (k>=1024) is identically zero: skip the loads entirely.
    const float nrm   = PIM14 * sqrtf(TWOPI_F * s / DT_S) * (1.f / N);
    const float wstep = TWOPI_F / ((float)N * DT_S);

    float2 w1[8], w2[8];
    #pragma unroll
    for (int i = 0; i < 4; ++i) {
        int   k = tid + i * NT;
        float f = 0.f;
        if (k >= 1) {
            float arg = s * (wstep * (float)k) - W0_C;
            f = nrm * __expf(-0.5f * arg * arg);
        }
        float2 a = yh1[k];
        float2 c = yh2[k];
        w1[i] = make_float2(a.x * f, a.y * f);
        w2[i] = make_float2(c.x * f, c.y * f);
    }
    #pragma unroll
    for (int i = 4; i < 8; ++i) {
        w1[i] = make_float2(0.f, 0.f);
        w2[i] = make_float2(0.f, 0.f);
    }
    fft2048_dual<+1, true>(w1, w2, U, V, tw, tid);   // W1, W2 in regs (fused pair)

    // pointwise products entirely in registers
    float2 P[8], C[8];
    #pragma unroll
    for (int i = 0; i < 8; ++i) {
        float2 a = w1[i], c = w2[i];
        P[i] = make_float2((a.x * a.x + a.y * a.y) * inv_s,
                           (c.x * c.x + c.y * c.y) * inv_s);
        C[i] = make_float2((a.x * c.x + a.y * c.y) * inv_s,
                           (a.y * c.x - a.x * c.y) * inv_s);
    }

    // Gaussian time-smoothing in Fourier domain (1/N folded into F)
    const float sdt = s / DT_S;
    const float fc  = -0.5f * sdt * sdt * (TWOPI_F / (float)N) * (TWOPI_F / (float)N);

    fft2048_dual<-1, false>(P, C, U, V, tw, tid);    // fused forward pair

    // filter computed once, applied to both P and C
    #pragma unroll
    for (int i = 0; i < 8; ++i) {
        int   k  = tid + i * NT;
        int   mk = min(k, N - k);
        float F  = __expf(fc * (float)(mk * mk)) * (1.f / N);
        P[i].x *= F; P[i].y *= F;
        C[i].x *= F; C[i].y *= F;
    }

    fft2048_dual<+1, false>(P, C, U, V, tw, tid);    // fused inverse pair: Psm, Csm in regs

    float4* To = T + ((size_t)bl * NSC + sidx) * N;
    #pragma unroll
    for (int i = 0; i < 8; ++i) {
        int k = tid + i * NT;
        // non-temporal: T is stream-once; do not evict spec from L2
        ntstore4(&To[k], make_float4(P[i].x, P[i].y, C[i].x, C[i].y));
    }
}

// ---------------- K3: scale-axis boxcar conv + coherence + partial scale sum
// 2-way scale split (doubles occupancy) + prefetch ring on the nt loads.
__global__ __launch_bounds__(NT) void k_coh(const float4* __restrict__ T,
                                            float* __restrict__ coh, int b0) {
    const int bl   = blockIdx.x >> 4;
    const int r    = blockIdx.x & 15;
    const int tile = r & 7;
    const int g    = r >> 3;
    const int t    = (tile << 8) + threadIdx.x;
    const int b    = b0 + bl;
    const float4* col = T + (size_t)bl * NSC * N + t;

    const int a    = g * 41;
    const int bEnd = (g == 0) ? 41 : NSC;

    float4 q[10];
    #pragma unroll
    for (int k = 0; k < 10; ++k) {
        int idx = a - 5 + k;
        q[k] = (idx >= 0 && idx < NSC) ? ntload4(&col[(size_t)idx * N])
                                       : make_float4(0.f, 0.f, 0.f, 0.f);
    }
    float4 p[4];
    #pragma unroll
    for (int j = 0; j < 4; ++j) {
        int idx = a + 5 + j;
        p[j] = (idx < NSC) ? ntload4(&col[(size_t)idx * N])
                           : make_float4(0.f, 0.f, 0.f, 0.f);
    }

    float acc = 0.f;
    const float w9 = 1.f / 9.f;
    for (int i = a; i < bEnd; ++i) {
        float sx = 0.f, sy = 0.f, sz = 0.f, sw = 0.f;
        #pragma unroll
        for (int k = 0; k < 10; ++k) { sx += q[k].x; sy += q[k].y; sz += q[k].z; sw += q[k].w; }
        float s1 = (sx - 0.5f * (q[0].x + q[9].x)) * w9;
        float s2 = (sy - 0.5f * (q[0].y + q[9].y)) * w9;
        float sr = (sz - 0.5f * (q[0].z + q[9].z)) * w9;
        float si = (sw - 0.5f * (q[0].w + q[9].w)) * w9;
        acc += (sr * sr + si * si) / (s1 * s2);
        #pragma unroll
        for (int k = 0; k < 9; ++k) q[k] = q[k + 1];
        q[9] = p[0];
        #pragma unroll
        for (int j = 0; j < 3; ++j) p[j] = p[j + 1];
        int c = i + 9;
        p[3] = (c < NSC) ? ntload4(&col[(size_t)c * N]) : make_float4(0.f, 0.f, 0.f, 0.f);
    }
    // partial sum plane g; k_win adds the two planes
    coh[((size_t)g * BATCH + b) * N + t] = acc;
}

// ---------------- K4: sliding-window sum via block-wide cumsum + diff -------
__global__ __launch_bounds__(NT) void k_win(const float* __restrict__ coh,
                                            float* __restrict__ out) {
    __shared__ float cs[N + 1];
    __shared__ float tot[NT];
    const int b   = blockIdx.x;
    const int tid = threadIdx.x;
    const float* r0 = coh + (size_t)b * N;
    const float* r1 = coh + (size_t)(BATCH + b) * N;

    // thread-local chunk [8*tid, 8*tid+8): load both planes, local inclusive scan
    float v[8];
    #pragma unroll
    for (int j = 0; j < 8; ++j) {
        int i = tid * 8 + j;
        v[j] = r0[i] + r1[i];
    }
    #pragma unroll
    for (int j = 1; j < 8; ++j) v[j] += v[j - 1];
    tot[tid] = v[7];
    __syncthreads();
    // Hillis-Steele inclusive scan over the 256 chunk totals
    for (int o = 1; o < NT; o <<= 1) {
        float tv = (tid >= o) ? tot[tid - o] : 0.f;
        __syncthreads();
        tot[tid] += tv;
        __syncthreads();
    }
    const float off = (tid > 0) ? tot[tid - 1] : 0.f;
    if (tid == 0) cs[0] = 0.f;
    #pragma unroll
    for (int j = 0; j < 8; ++j) cs[tid * 8 + j + 1] = off + v[j];
    __syncthreads();
    for (int t0 = tid; t0 < NOUT; t0 += NT)
        out[(size_t)b * NOUT + t0] = cs[t0 + WS_WIN] - cs[t0];
}

// ---------------- host launcher ----------------
extern "C" void kernel_launch(void* const* d_in, const int* in_sizes, int n_in,
                              void* d_out, int out_size, void* d_ws, size_t ws_size,
                              hipStream_t stream) {
    const float* x   = (const float*)d_in[0];
    float*       out = (float*)d_out;
    char*        ws  = (char*)d_ws;

    const size_t spec_bytes = (size_t)BATCH * 2 * N * sizeof(float2); // 2 MB
    const size_t coh_bytes  = (size_t)2 * BATCH * N * sizeof(float);  // 1 MB (2 planes)
    const size_t perBatchT  = (size_t)NSC * N * sizeof(float4);       // ~2.65 MB

    float2* spec = (float2*)ws;
    float*  coh  = (float*)(ws + spec_bytes);
    float4* T    = (float4*)(ws + spec_bytes + coh_bytes);

    size_t avail = (ws_size > spec_bytes + coh_bytes) ? (ws_size - spec_bytes - coh_bytes) : 0;
    int chunk = (int)(avail / perBatchT);
    if (chunk < 1) chunk = 1;
    if (chunk > BATCH) chunk = BATCH;

    k_fft_in<<<BATCH * 2, NT, 0, stream>>>(x, spec);
    for (int b0 = 0; b0 < BATCH; b0 += chunk) {
        int cb = BATCH - b0 < chunk ? BATCH - b0 : chunk;
        k_wct<<<cb * NSC, NT, 0, stream>>>(spec, T, b0);
        k_coh<<<cb * 16, NT, 0, stream>>>(T, coh, b0);
    }
    k_win<<<BATCH, NT, 0, stream>>>(coh, out);
}

// Round 7
// 179.272 us; speedup vs baseline: 1.0140x; 1.0140x over previous
//
#include <hip/hip_runtime.h>
#include <math.h>

// ---------------- problem constants ----------------
#define N        2048
#define NT       256      // threads per block
#define NSC      81       // number of scales (J+1)
#define BATCH    64
#define WS_WIN   94       // sliding window = 32*3-2
#define NOUT     1955     // N - WS_WIN + 1
#define DT_S     0.1f
#define W0_C     6.0f
#define PI_F     3.14159265358979f
#define TWOPI_F  6.28318530717959f
#define PIM14    0.7511255444649425f   // pi^(-1/4)
#define C_SQ2H   0.70710678118654752f  // sqrt(2)/2

// pad-swizzle: +1 element every 16 keeps every stage's b64 pattern at the
// 4-lane/bank-pair bandwidth floor (R4-measured good; XOR swizzle regressed)
#define SWZ(e)   ((e) + ((e) >> 4))
#define LDSN     2176     // 2048 + 128 pad elements

typedef float f4v __attribute__((ext_vector_type(4)));
typedef unsigned int u2v __attribute__((ext_vector_type(2)));

__device__ __forceinline__ u2v ntload2(const u2v* p) {
    return __builtin_nontemporal_load(p);
}
__device__ __forceinline__ void ntstore2(u2v* p, u2v v) {
    __builtin_nontemporal_store(v, p);
}

// pack 4 floats to 4 bf16 (round-to-nearest via +0x8000) in 8 bytes.
// Coherence ratio is invariant to T's precision scale; bf16 keeps fp32 range.
__device__ __forceinline__ u2v pack4(float a, float b, float c, float d) {
    unsigned ua = (__float_as_uint(a) + 0x8000u) >> 16;
    unsigned ub = (__float_as_uint(b) + 0x8000u) & 0xffff0000u;
    unsigned uc = (__float_as_uint(c) + 0x8000u) >> 16;
    unsigned ud = (__float_as_uint(d) + 0x8000u) & 0xffff0000u;
    u2v r; r.x = ua | ub; r.y = uc | ud;
    return r;
}
__device__ __forceinline__ float4 unpack4(u2v w) {
    return make_float4(__uint_as_float(w.x << 16),
                       __uint_as_float(w.x & 0xffff0000u),
                       __uint_as_float(w.y << 16),
                       __uint_as_float(w.y & 0xffff0000u));
}

__device__ __forceinline__ float2 cadd2(float2 a, float2 b) { return make_float2(a.x + b.x, a.y + b.y); }
__device__ __forceinline__ float2 csub2(float2 a, float2 b) { return make_float2(a.x - b.x, a.y - b.y); }
__device__ __forceinline__ float2 cmul2(float2 a, float2 b) { return make_float2(a.x * b.x - a.y * b.y, a.x * b.y + a.y * b.x); }

// ---------------- precomputed twiddles ----------------
// Per thread, the 3 twiddled stages of the 2048-pt FFT use fixed angles:
//   stage1 (m=1):  jm = tid;  stage2 (m=8): jm = tid&~7;  stage3 (m=64): jm = tid&~63
// Store w^1..w^7 at SGN=-1 once; SGN=+1 passes use the conjugate (free).
struct Tw { float2 w[3][7]; };

__device__ __forceinline__ void tw_init(Tw& tw, int tid) {
    const int jms[3] = { tid, tid & ~7, tid & ~63 };
    #pragma unroll
    for (int t = 0; t < 3; ++t) {
        float ang = -(TWOPI_F / (float)N) * (float)jms[t];  // SGN=-1 base
        float sn, cs; __sincosf(ang, &sn, &cs);
        float2 w1 = make_float2(cs, sn);
        tw.w[t][0] = w1;
        #pragma unroll
        for (int p = 1; p < 7; ++p) tw.w[t][p] = cmul2(tw.w[t][p - 1], w1);
    }
}

// multiply by stored twiddle (SGN=-1) or its conjugate (SGN=+1)
template<int SGN>
__device__ __forceinline__ float2 cmul_tw(float2 a, float2 w) {
    if (SGN < 0) return make_float2(a.x * w.x - a.y * w.y, a.x * w.y + a.y * w.x);
    else         return make_float2(a.x * w.x + a.y * w.y, a.y * w.x - a.x * w.y);
}

// 8-point DFT, natural-order outputs (sign SGN).
// HALF=true: x[4..7] are known zero (one-sided spectrum input).
template<int SGN, bool HALF>
__device__ __forceinline__ void dft8(const float2 (&x)[8], float2 (&y)[8]) {
    const float s = (float)SGN;
    float2 t0, t1, t2, t3, u0, d1, d2, d3;
    if (HALF) {
        t0 = x[0]; t1 = x[1]; t2 = x[2]; t3 = x[3];
        u0 = x[0]; d1 = x[1]; d2 = x[2]; d3 = x[3];
    } else {
        t0 = cadd2(x[0], x[4]); t1 = cadd2(x[1], x[5]);
        t2 = cadd2(x[2], x[6]); t3 = cadd2(x[3], x[7]);
        u0 = csub2(x[0], x[4]);
        d1 = csub2(x[1], x[5]);
        d2 = csub2(x[2], x[6]);
        d3 = csub2(x[3], x[7]);
    }
    float2 u1 = make_float2(C_SQ2H * (d1.x - s * d1.y), C_SQ2H * (d1.y + s * d1.x));
    float2 u2 = make_float2(-s * d2.y, s * d2.x);
    float2 u3 = make_float2(-C_SQ2H * (d3.x + s * d3.y), C_SQ2H * (s * d3.x - d3.y));
    float2 a0 = cadd2(t0, t2), a1 = cadd2(t1, t3), b0 = csub2(t0, t2), e1 = csub2(t1, t3);
    float2 b1 = make_float2(-s * e1.y, s * e1.x);
    y[0] = cadd2(a0, a1); y[4] = csub2(a0, a1); y[2] = cadd2(b0, b1); y[6] = csub2(b0, b1);
    float2 c0 = cadd2(u0, u2), c1 = cadd2(u1, u3), g0 = csub2(u0, u2), h1 = csub2(u1, u3);
    float2 g1 = make_float2(-s * h1.y, s * h1.x);
    y[1] = cadd2(c0, c1); y[5] = csub2(c0, c1); y[3] = cadd2(g0, g1); y[7] = csub2(g0, g1);
}

// apply precomputed twiddles and scatter-store
template<int SGN>
__device__ __forceinline__ void twiddle_store(const float2 (&y)[8], float2* __restrict__ dst,
                                              const float2 (&w)[7], int base, int m) {
    dst[SWZ(base)] = y[0];
    #pragma unroll
    for (int p = 1; p < 8; ++p)
        dst[SWZ(base + p * m)] = cmul_tw<SGN>(y[p], w[p - 1]);
}

// stage 1 (m=1): input from registers x[p] = element tid + p*256
template<int SGN, bool HALF>
__device__ __forceinline__ void stage1_reg(const float2 (&x)[8], float2* __restrict__ dst,
                                           const Tw& tw, int tid) {
    float2 y[8];
    dft8<SGN, HALF>(x, y);
    twiddle_store<SGN>(y, dst, tw.w[0], 8 * tid, 1);
}

// split middle stage: read phase (gather 8) -- must be followed by a barrier
// before the in-place write phase
__device__ __forceinline__ void stage_read(const float2* __restrict__ src, float2 (&x)[8], int q) {
    #pragma unroll
    for (int p = 0; p < 8; ++p) x[p] = src[SWZ(q + p * 256)];
}

// split middle stage: dft + twiddle + in-place scatter write. TWS: 1 for m=8, 2 for m=64
template<int SGN, int TWS>
__device__ __forceinline__ void stage_write(float2* __restrict__ dst, const float2 (&x)[8],
                                            const Tw& tw, int q) {
    float2 y[8];
    dft8<SGN, false>(x, y);
    const int m  = (TWS == 1) ? 8 : 64;
    const int jm = q & ~(m - 1);
    twiddle_store<SGN>(y, dst, tw.w[TWS], q + 7 * jm, m);
}

// final radix-4 stage (m=512, j=0, no twiddles): outputs land back in regs,
// x[2u+qq] = element tid + (2u+qq)*256  (natural order, thread-owned)
template<int SGN>
__device__ __forceinline__ void stage4_regs(const float2* __restrict__ src, float2 (&x)[8], int tid) {
    const float s = (float)SGN;
    #pragma unroll
    for (int qq = 0; qq < 2; ++qq) {
        int q = tid + qq * 256;
        float2 x0 = src[SWZ(q)];
        float2 x1 = src[SWZ(q + 512)];
        float2 x2 = src[SWZ(q + 1024)];
        float2 x3 = src[SWZ(q + 1536)];
        float2 a0 = cadd2(x0, x2), a1 = cadd2(x1, x3);
        float2 b0 = csub2(x0, x2), e1 = csub2(x1, x3);
        float2 b1 = make_float2(-s * e1.y, s * e1.x);
        x[0 + qq] = cadd2(a0, a1);
        x[2 + qq] = cadd2(b0, b1);
        x[4 + qq] = csub2(a0, a1);
        x[6 + qq] = csub2(b0, b1);
    }
}

// fused dual-signal 2048-pt FFT, register in / register out.
// In-place per-signal buffers (U, V), read-phase/write-phase split per stage.
// SGN=-1: forward (numpy fft). SGN=+1: inverse exponent (1/N not applied).
// HALF=true: inputs' upper halves (elements k>=1024) are zero.
template<int SGN, bool HALF>
__device__ __forceinline__ void fft2048_dual(float2 (&u)[8], float2 (&v)[8],
                                             float2* U, float2* V, const Tw& tw, int tid) {
    __syncthreads();                        // protect buffers from previous pass's reads
    stage1_reg<SGN, HALF>(u, U, tw, tid);   // regs -> U/V   (m=1)
    stage1_reg<SGN, HALF>(v, V, tw, tid);
    __syncthreads();
    float2 xu[8], xv[8];
    stage_read(U, xu, tid);                 // m=8 read
    stage_read(V, xv, tid);
    __syncthreads();
    stage_write<SGN, 1>(U, xu, tw, tid);    // m=8 write (in place)
    stage_write<SGN, 1>(V, xv, tw, tid);
    __syncthreads();
    stage_read(U, xu, tid);                 // m=64 read
    stage_read(V, xv, tid);
    __syncthreads();
    stage_write<SGN, 2>(U, xu, tw, tid);    // m=64 write (in place)
    stage_write<SGN, 2>(V, xv, tw, tid);
    __syncthreads();
    stage4_regs<SGN>(U, u, tid);            // m=512 -> regs
    stage4_regs<SGN>(V, v, tid);
}

// single-signal variant (k_fft_in), same in-place structure, one buffer
template<int SGN>
__device__ __forceinline__ void fft2048_single(float2 (&u)[8], float2* U, const Tw& tw, int tid) {
    __syncthreads();
    stage1_reg<SGN, false>(u, U, tw, tid);
    __syncthreads();
    float2 x[8];
    stage_read(U, x, tid);
    __syncthreads();
    stage_write<SGN, 1>(U, x, tw, tid);
    __syncthreads();
    stage_read(U, x, tid);
    __syncthreads();
    stage_write<SGN, 2>(U, x, tw, tid);
    __syncthreads();
    stage4_regs<SGN>(U, u, tid);
}

// ---------------- K1: normalize + forward FFT of each signal ----------------
__global__ __launch_bounds__(NT) void k_fft_in(const float* __restrict__ x,
                                               float2* __restrict__ spec) {
    __shared__ float2 A[LDSN];
    __shared__ float rs[4], rq[4];
    const int    tid = threadIdx.x;
    const float* y   = x + (size_t)blockIdx.x * N;

    Tw tw; tw_init(tw, tid);

    float v[8];
    float lsum = 0.f, lsq = 0.f;
    #pragma unroll
    for (int i = 0; i < 8; ++i) {
        float t = y[tid + i * NT];
        v[i] = t; lsum += t; lsq += t * t;
    }
    // wave butterfly reduce, then 4 partials through LDS (1 barrier)
    #pragma unroll
    for (int o = 1; o < 64; o <<= 1) {
        lsum += __shfl_xor(lsum, o, 64);
        lsq  += __shfl_xor(lsq,  o, 64);
    }
    const int wid = tid >> 6, lane = tid & 63;
    if (lane == 0) { rs[wid] = lsum; rq[wid] = lsq; }
    __syncthreads();
    const float fsum = rs[0] + rs[1] + rs[2] + rs[3];
    const float fsq  = rq[0] + rq[1] + rq[2] + rq[3];
    const float mean = fsum * (1.f / N);
    const float var  = fsq * (1.f / N) - mean * mean;
    const float inv  = rsqrtf(var);

    float2 z[8];
    #pragma unroll
    for (int i = 0; i < 8; ++i) z[i] = make_float2((v[i] - mean) * inv, 0.f);

    fft2048_single<-1>(z, A, tw, tid);

    float2* o2 = spec + (size_t)blockIdx.x * N;
    #pragma unroll
    for (int i = 0; i < 8; ++i) o2[tid + i * NT] = z[i];   // spec is hot: keep cached
}

// ---------------- K2: per (batch, scale) CWT + smoothing ----------------
__global__ __launch_bounds__(NT, 4) void k_wct(const float2* __restrict__ spec,
                                               u2v* __restrict__ T, int b0) {
    __shared__ float2 U[LDSN];
    __shared__ float2 V[LDSN];
    const int tid  = threadIdx.x;
    const int sidx = blockIdx.x % NSC;
    const int bl   = blockIdx.x / NSC;
    const int b    = b0 + bl;

    Tw tw; tw_init(tw, tid);

    const float s0    = 2.f * DT_S * (W0_C + sqrtf(2.f + W0_C * W0_C)) / (4.f * PI_F);
    const float s     = s0 * exp2f(0.125f * (float)sidx);
    const float inv_s = 1.f / s;

    const float2* yh1 = spec + (size_t)(b * 2 + 0) * N;
    const float2* yh2 = spec + (size_t)(b * 2 + 1) * N;

    // Morlet filter (w>0 one-sided), unit-energy norm, ifft 1/N folded in.
    // Upper half (k>=1024) is identically zero: skip the loads entirely.
    const float nrm   = PIM14 * sqrtf(TWOPI_F * s / DT_S) * (1.f / N);
    const float wstep = TWOPI_F / ((float)N * DT_S);

    float2 w1[8], w2[8];
    #pragma unroll
    for (int i = 0; i < 4; ++i) {
        int   k = tid + i * NT;
        float f = 0.f;
        if (k >= 1) {
            float arg = s * (wstep * (float)k) - W0_C;
            f = nrm * __expf(-0.5f * arg * arg);
        }
        float2 a = yh1[k];
        float2 c = yh2[k];
        w1[i] = make_float2(a.x * f, a.y * f);
        w2[i] = make_float2(c.x * f, c.y * f);
    }
    #pragma unroll
    for (int i = 4; i < 8; ++i) {
        w1[i] = make_float2(0.f, 0.f);
        w2[i] = make_float2(0.f, 0.f);
    }
    fft2048_dual<+1, true>(w1, w2, U, V, tw, tid);   // W1, W2 in regs (fused pair)

    // pointwise products entirely in registers
    float2 P[8], C[8];
    #pragma unroll
    for (int i = 0; i < 8; ++i) {
        float2 a = w1[i], c = w2[i];
        P[i] = make_float2((a.x * a.x + a.y * a.y) * inv_s,
                           (c.x * c.x + c.y * c.y) * inv_s);
        C[i] = make_float2((a.x * c.x + a.y * c.y) * inv_s,
                           (a.y * c.x - a.x * c.y) * inv_s);
    }

    // Gaussian time-smoothing in Fourier domain (1/N folded into F)
    const float sdt = s / DT_S;
    const float fc  = -0.5f * sdt * sdt * (TWOPI_F / (float)N) * (TWOPI_F / (float)N);

    fft2048_dual<-1, false>(P, C, U, V, tw, tid);    // fused forward pair

    // filter computed once, applied to both P and C
    #pragma unroll
    for (int i = 0; i < 8; ++i) {
        int   k  = tid + i * NT;
        int   mk = min(k, N - k);
        float F  = __expf(fc * (float)(mk * mk)) * (1.f / N);
        P[i].x *= F; P[i].y *= F;
        C[i].x *= F; C[i].y *= F;
    }

    fft2048_dual<+1, false>(P, C, U, V, tw, tid);    // fused inverse pair: Psm, Csm in regs

    u2v* To = T + ((size_t)bl * NSC + sidx) * N;
    #pragma unroll
    for (int i = 0; i < 8; ++i) {
        int k = tid + i * NT;
        // bf16x4 packed, non-temporal: T is stream-once; coherence ratio is
        // quadratic-over-quadratic in T, so bf16's 0.2% rel. error survives.
        ntstore2(&To[k], pack4(P[i].x, P[i].y, C[i].x, C[i].y));
    }
}

// ---------------- K3: scale-axis boxcar conv + coherence + partial scale sum
// 2-way scale split (doubles occupancy) + prefetch ring on the nt loads.
__global__ __launch_bounds__(NT) void k_coh(const u2v* __restrict__ T,
                                            float* __restrict__ coh, int b0) {
    const int bl   = blockIdx.x >> 4;
    const int r    = blockIdx.x & 15;
    const int tile = r & 7;
    const int g    = r >> 3;
    const int t    = (tile << 8) + threadIdx.x;
    const int b    = b0 + bl;
    const u2v* col = T + (size_t)bl * NSC * N + t;

    const int a    = g * 41;
    const int bEnd = (g == 0) ? 41 : NSC;

    float4 q[10];
    #pragma unroll
    for (int k = 0; k < 10; ++k) {
        int idx = a - 5 + k;
        q[k] = (idx >= 0 && idx < NSC) ? unpack4(ntload2(&col[(size_t)idx * N]))
                                       : make_float4(0.f, 0.f, 0.f, 0.f);
    }
    float4 p[4];
    #pragma unroll
    for (int j = 0; j < 4; ++j) {
        int idx = a + 5 + j;
        p[j] = (idx < NSC) ? unpack4(ntload2(&col[(size_t)idx * N]))
                           : make_float4(0.f, 0.f, 0.f, 0.f);
    }

    float acc = 0.f;
    const float w9 = 1.f / 9.f;
    for (int i = a; i < bEnd; ++i) {
        float sx = 0.f, sy = 0.f, sz = 0.f, sw = 0.f;
        #pragma unroll
        for (int k = 0; k < 10; ++k) { sx += q[k].x; sy += q[k].y; sz += q[k].z; sw += q[k].w; }
        float s1 = (sx - 0.5f * (q[0].x + q[9].x)) * w9;
        float s2 = (sy - 0.5f * (q[0].y + q[9].y)) * w9;
        float sr = (sz - 0.5f * (q[0].z + q[9].z)) * w9;
        float si = (sw - 0.5f * (q[0].w + q[9].w)) * w9;
        acc += (sr * sr + si * si) / (s1 * s2);
        #pragma unroll
        for (int k = 0; k < 9; ++k) q[k] = q[k + 1];
        q[9] = p[0];
        #pragma unroll
        for (int j = 0; j < 3; ++j) p[j] = p[j + 1];
        int c = i + 9;
        p[3] = (c < NSC) ? unpack4(ntload2(&col[(size_t)c * N])) : make_float4(0.f, 0.f, 0.f, 0.f);
    }
    // partial sum plane g; k_win adds the two planes
    coh[((size_t)g * BATCH + b) * N + t] = acc;
}

// ---------------- K4: sliding-window sum via block-wide cumsum + diff -------
__global__ __launch_bounds__(NT) void k_win(const float* __restrict__ coh,
                                            float* __restrict__ out) {
    __shared__ float cs[N + 1];
    __shared__ float tot[NT];
    const int b   = blockIdx.x;
    const int tid = threadIdx.x;
    const float* r0 = coh + (size_t)b * N;
    const float* r1 = coh + (size_t)(BATCH + b) * N;

    // thread-local chunk [8*tid, 8*tid+8): load both planes, local inclusive scan
    float v[8];
    #pragma unroll
    for (int j = 0; j < 8; ++j) {
        int i = tid * 8 + j;
        v[j] = r0[i] + r1[i];
    }
    #pragma unroll
    for (int j = 1; j < 8; ++j) v[j] += v[j - 1];
    tot[tid] = v[7];
    __syncthreads();
    // Hillis-Steele inclusive scan over the 256 chunk totals
    for (int o = 1; o < NT; o <<= 1) {
        float tv = (tid >= o) ? tot[tid - o] : 0.f;
        __syncthreads();
        tot[tid] += tv;
        __syncthreads();
    }
    const float off = (tid > 0) ? tot[tid - 1] : 0.f;
    if (tid == 0) cs[0] = 0.f;
    #pragma unroll
    for (int j = 0; j < 8; ++j) cs[tid * 8 + j + 1] = off + v[j];
    __syncthreads();
    for (int t0 = tid; t0 < NOUT; t0 += NT)
        out[(size_t)b * NOUT + t0] = cs[t0 + WS_WIN] - cs[t0];
}

// ---------------- host launcher ----------------
extern "C" void kernel_launch(void* const* d_in, const int* in_sizes, int n_in,
                              void* d_out, int out_size, void* d_ws, size_t ws_size,
                              hipStream_t stream) {
    const float* x   = (const float*)d_in[0];
    float*       out = (float*)d_out;
    char*        ws  = (char*)d_ws;

    const size_t spec_bytes = (size_t)BATCH * 2 * N * sizeof(float2); // 2 MB
    const size_t coh_bytes  = (size_t)2 * BATCH * N * sizeof(float);  // 1 MB (2 planes)
    const size_t perBatchT  = (size_t)NSC * N * sizeof(u2v);          // ~1.33 MB (bf16x4)

    float2* spec = (float2*)ws;
    float*  coh  = (float*)(ws + spec_bytes);
    u2v*    T    = (u2v*)(ws + spec_bytes + coh_bytes);

    size_t avail = (ws_size > spec_bytes + coh_bytes) ? (ws_size - spec_bytes - coh_bytes) : 0;
    int chunk = (int)(avail / perBatchT);
    if (chunk < 1) chunk = 1;
    if (chunk > BATCH) chunk = BATCH;

    k_fft_in<<<BATCH * 2, NT, 0, stream>>>(x, spec);
    for (int b0 = 0; b0 < BATCH; b0 += chunk) {
        int cb = BATCH - b0 < chunk ? BATCH - b0 : chunk;
        k_wct<<<cb * NSC, NT, 0, stream>>>(spec, T, b0);
        k_coh<<<cb * 16, NT, 0, stream>>>(T, coh, b0);
    }
    k_win<<<BATCH, NT, 0, stream>>>(coh, out);
}

// Round 8
// 155.600 us; speedup vs baseline: 1.1683x; 1.1521x over previous
//
#include <hip/hip_runtime.h>
#include <math.h>

// ---------------- problem constants ----------------
#define N        2048
#define NT       256      // threads per block
#define NSC      81       // number of scales (J+1)
#define BATCH    64
#define WS_WIN   94       // sliding window = 32*3-2
#define NOUT     1955     // N - WS_WIN + 1
#define DT_S     0.1f
#define W0_C     6.0f
#define PI_F     3.14159265358979f
#define TWOPI_F  6.28318530717959f
#define PIM14    0.7511255444649425f   // pi^(-1/4)
#define C_SQ2H   0.70710678118654752f  // sqrt(2)/2

// pad-swizzle: +1 element every 16 keeps every stage's b64 pattern at the
// 4-lane/bank-pair bandwidth floor (R4-measured good; XOR swizzle regressed)
#define SWZ(e)   ((e) + ((e) >> 4))
#define LDSN     2176     // 2048 + 128 pad elements

typedef float f4v __attribute__((ext_vector_type(4)));
typedef unsigned int u2v __attribute__((ext_vector_type(2)));

__device__ __forceinline__ u2v ntload2(const u2v* p) {
    return __builtin_nontemporal_load(p);
}
__device__ __forceinline__ void ntstore2(u2v* p, u2v v) {
    __builtin_nontemporal_store(v, p);
}

// pack 4 floats to 4 bf16 (round-to-nearest via +0x8000) in 8 bytes.
// Coherence ratio is invariant to T's precision scale; bf16 keeps fp32 range.
__device__ __forceinline__ u2v pack4(float a, float b, float c, float d) {
    unsigned ua = (__float_as_uint(a) + 0x8000u) >> 16;
    unsigned ub = (__float_as_uint(b) + 0x8000u) & 0xffff0000u;
    unsigned uc = (__float_as_uint(c) + 0x8000u) >> 16;
    unsigned ud = (__float_as_uint(d) + 0x8000u) & 0xffff0000u;
    u2v r; r.x = ua | ub; r.y = uc | ud;
    return r;
}
__device__ __forceinline__ float4 unpack4(u2v w) {
    return make_float4(__uint_as_float(w.x << 16),
                       __uint_as_float(w.x & 0xffff0000u),
                       __uint_as_float(w.y << 16),
                       __uint_as_float(w.y & 0xffff0000u));
}

__device__ __forceinline__ float2 cadd2(float2 a, float2 b) { return make_float2(a.x + b.x, a.y + b.y); }
__device__ __forceinline__ float2 csub2(float2 a, float2 b) { return make_float2(a.x - b.x, a.y - b.y); }
__device__ __forceinline__ float2 cmul2(float2 a, float2 b) { return make_float2(a.x * b.x - a.y * b.y, a.x * b.y + a.y * b.x); }

// ---------------- precomputed twiddles ----------------
// Per thread, the 3 twiddled stages of the 2048-pt FFT use fixed angles:
//   stage1 (m=1):  jm = tid;  stage2 (m=8): jm = tid&~7;  stage3 (m=64): jm = tid&~63
// Store w^1..w^7 at SGN=-1 once; SGN=+1 passes use the conjugate (free).
struct Tw { float2 w[3][7]; };

__device__ __forceinline__ void tw_init(Tw& tw, int tid) {
    const int jms[3] = { tid, tid & ~7, tid & ~63 };
    #pragma unroll
    for (int t = 0; t < 3; ++t) {
        float ang = -(TWOPI_F / (float)N) * (float)jms[t];  // SGN=-1 base
        float sn, cs; __sincosf(ang, &sn, &cs);
        float2 w1 = make_float2(cs, sn);
        tw.w[t][0] = w1;
        #pragma unroll
        for (int p = 1; p < 7; ++p) tw.w[t][p] = cmul2(tw.w[t][p - 1], w1);
    }
}

// multiply by stored twiddle (SGN=-1) or its conjugate (SGN=+1)
template<int SGN>
__device__ __forceinline__ float2 cmul_tw(float2 a, float2 w) {
    if (SGN < 0) return make_float2(a.x * w.x - a.y * w.y, a.x * w.y + a.y * w.x);
    else         return make_float2(a.x * w.x + a.y * w.y, a.y * w.x - a.x * w.y);
}

// 8-point DFT, natural-order outputs (sign SGN).
// HALF=true: x[4..7] are known zero (one-sided spectrum input).
template<int SGN, bool HALF>
__device__ __forceinline__ void dft8(const float2 (&x)[8], float2 (&y)[8]) {
    const float s = (float)SGN;
    float2 t0, t1, t2, t3, u0, d1, d2, d3;
    if (HALF) {
        t0 = x[0]; t1 = x[1]; t2 = x[2]; t3 = x[3];
        u0 = x[0]; d1 = x[1]; d2 = x[2]; d3 = x[3];
    } else {
        t0 = cadd2(x[0], x[4]); t1 = cadd2(x[1], x[5]);
        t2 = cadd2(x[2], x[6]); t3 = cadd2(x[3], x[7]);
        u0 = csub2(x[0], x[4]);
        d1 = csub2(x[1], x[5]);
        d2 = csub2(x[2], x[6]);
        d3 = csub2(x[3], x[7]);
    }
    float2 u1 = make_float2(C_SQ2H * (d1.x - s * d1.y), C_SQ2H * (d1.y + s * d1.x));
    float2 u2 = make_float2(-s * d2.y, s * d2.x);
    float2 u3 = make_float2(-C_SQ2H * (d3.x + s * d3.y), C_SQ2H * (s * d3.x - d3.y));
    float2 a0 = cadd2(t0, t2), a1 = cadd2(t1, t3), b0 = csub2(t0, t2), e1 = csub2(t1, t3);
    float2 b1 = make_float2(-s * e1.y, s * e1.x);
    y[0] = cadd2(a0, a1); y[4] = csub2(a0, a1); y[2] = cadd2(b0, b1); y[6] = csub2(b0, b1);
    float2 c0 = cadd2(u0, u2), c1 = cadd2(u1, u3), g0 = csub2(u0, u2), h1 = csub2(u1, u3);
    float2 g1 = make_float2(-s * h1.y, s * h1.x);
    y[1] = cadd2(c0, c1); y[5] = csub2(c0, c1); y[3] = cadd2(g0, g1); y[7] = csub2(g0, g1);
}

// apply precomputed twiddles and scatter-store
template<int SGN>
__device__ __forceinline__ void twiddle_store(const float2 (&y)[8], float2* __restrict__ dst,
                                              const float2 (&w)[7], int base, int m) {
    dst[SWZ(base)] = y[0];
    #pragma unroll
    for (int p = 1; p < 8; ++p)
        dst[SWZ(base + p * m)] = cmul_tw<SGN>(y[p], w[p - 1]);
}

// stage 1 (m=1): input from registers x[p] = element tid + p*256
template<int SGN, bool HALF>
__device__ __forceinline__ void stage1_reg(const float2 (&x)[8], float2* __restrict__ dst,
                                           const Tw& tw, int tid) {
    float2 y[8];
    dft8<SGN, HALF>(x, y);
    twiddle_store<SGN>(y, dst, tw.w[0], 8 * tid, 1);
}

// split middle stage: read phase (gather 8) -- must be followed by a barrier
// before the in-place write phase
__device__ __forceinline__ void stage_read(const float2* __restrict__ src, float2 (&x)[8], int q) {
    #pragma unroll
    for (int p = 0; p < 8; ++p) x[p] = src[SWZ(q + p * 256)];
}

// split middle stage: dft + twiddle + in-place scatter write. TWS: 1 for m=8, 2 for m=64
template<int SGN, int TWS>
__device__ __forceinline__ void stage_write(float2* __restrict__ dst, const float2 (&x)[8],
                                            const Tw& tw, int q) {
    float2 y[8];
    dft8<SGN, false>(x, y);
    const int m  = (TWS == 1) ? 8 : 64;
    const int jm = q & ~(m - 1);
    twiddle_store<SGN>(y, dst, tw.w[TWS], q + 7 * jm, m);
}

// final radix-4 stage (m=512, j=0, no twiddles): outputs land back in regs,
// x[2u+qq] = element tid + (2u+qq)*256  (natural order, thread-owned)
template<int SGN>
__device__ __forceinline__ void stage4_regs(const float2* __restrict__ src, float2 (&x)[8], int tid) {
    const float s = (float)SGN;
    #pragma unroll
    for (int qq = 0; qq < 2; ++qq) {
        int q = tid + qq * 256;
        float2 x0 = src[SWZ(q)];
        float2 x1 = src[SWZ(q + 512)];
        float2 x2 = src[SWZ(q + 1024)];
        float2 x3 = src[SWZ(q + 1536)];
        float2 a0 = cadd2(x0, x2), a1 = cadd2(x1, x3);
        float2 b0 = csub2(x0, x2), e1 = csub2(x1, x3);
        float2 b1 = make_float2(-s * e1.y, s * e1.x);
        x[0 + qq] = cadd2(a0, a1);
        x[2 + qq] = cadd2(b0, b1);
        x[4 + qq] = csub2(a0, a1);
        x[6 + qq] = csub2(b0, b1);
    }
}

// fused dual-signal 2048-pt FFT, register in / register out.
// In-place per-signal buffers (U, V), read-phase/write-phase split per stage.
// SGN=-1: forward (numpy fft). SGN=+1: inverse exponent (1/N not applied).
// HALF=true: inputs' upper halves (elements k>=1024) are zero.
template<int SGN, bool HALF>
__device__ __forceinline__ void fft2048_dual(float2 (&u)[8], float2 (&v)[8],
                                             float2* U, float2* V, const Tw& tw, int tid) {
    __syncthreads();                        // protect buffers from previous pass's reads
    stage1_reg<SGN, HALF>(u, U, tw, tid);   // regs -> U/V   (m=1)
    stage1_reg<SGN, HALF>(v, V, tw, tid);
    __syncthreads();
    float2 xu[8], xv[8];
    stage_read(U, xu, tid);                 // m=8 read
    stage_read(V, xv, tid);
    __syncthreads();
    stage_write<SGN, 1>(U, xu, tw, tid);    // m=8 write (in place)
    stage_write<SGN, 1>(V, xv, tw, tid);
    __syncthreads();
    stage_read(U, xu, tid);                 // m=64 read
    stage_read(V, xv, tid);
    __syncthreads();
    stage_write<SGN, 2>(U, xu, tw, tid);    // m=64 write (in place)
    stage_write<SGN, 2>(V, xv, tw, tid);
    __syncthreads();
    stage4_regs<SGN>(U, u, tid);            // m=512 -> regs
    stage4_regs<SGN>(V, v, tid);
}

// single-signal variant (k_fft_in), same in-place structure, one buffer
template<int SGN>
__device__ __forceinline__ void fft2048_single(float2 (&u)[8], float2* U, const Tw& tw, int tid) {
    __syncthreads();
    stage1_reg<SGN, false>(u, U, tw, tid);
    __syncthreads();
    float2 x[8];
    stage_read(U, x, tid);
    __syncthreads();
    stage_write<SGN, 1>(U, x, tw, tid);
    __syncthreads();
    stage_read(U, x, tid);
    __syncthreads();
    stage_write<SGN, 2>(U, x, tw, tid);
    __syncthreads();
    stage4_regs<SGN>(U, u, tid);
}

// ---------------- K1: normalize + forward FFT of each signal ----------------
__global__ __launch_bounds__(NT) void k_fft_in(const float* __restrict__ x,
                                               float2* __restrict__ spec) {
    __shared__ float2 A[LDSN];
    __shared__ float rs[4], rq[4];
    const int    tid = threadIdx.x;
    const float* y   = x + (size_t)blockIdx.x * N;

    Tw tw; tw_init(tw, tid);

    float v[8];
    float lsum = 0.f, lsq = 0.f;
    #pragma unroll
    for (int i = 0; i < 8; ++i) {
        float t = y[tid + i * NT];
        v[i] = t; lsum += t; lsq += t * t;
    }
    // wave butterfly reduce, then 4 partials through LDS (1 barrier)
    #pragma unroll
    for (int o = 1; o < 64; o <<= 1) {
        lsum += __shfl_xor(lsum, o, 64);
        lsq  += __shfl_xor(lsq,  o, 64);
    }
    const int wid = tid >> 6, lane = tid & 63;
    if (lane == 0) { rs[wid] = lsum; rq[wid] = lsq; }
    __syncthreads();
    const float fsum = rs[0] + rs[1] + rs[2] + rs[3];
    const float fsq  = rq[0] + rq[1] + rq[2] + rq[3];
    const float mean = fsum * (1.f / N);
    const float var  = fsq * (1.f / N) - mean * mean;
    const float inv  = rsqrtf(var);

    float2 z[8];
    #pragma unroll
    for (int i = 0; i < 8; ++i) z[i] = make_float2((v[i] - mean) * inv, 0.f);

    fft2048_single<-1>(z, A, tw, tid);

    float2* o2 = spec + (size_t)blockIdx.x * N;
    #pragma unroll
    for (int i = 0; i < 8; ++i) o2[tid + i * NT] = z[i];   // spec is hot: keep cached
}

// ---------------- K2: per (batch, scale) CWT + smoothing ----------------
__global__ __launch_bounds__(NT, 4) void k_wct(const float2* __restrict__ spec,
                                               u2v* __restrict__ T, int b0) {
    __shared__ float2 U[LDSN];
    __shared__ float2 V[LDSN];
    const int tid  = threadIdx.x;
    const int sidx = blockIdx.x % NSC;
    const int bl   = blockIdx.x / NSC;
    const int b    = b0 + bl;

    Tw tw; tw_init(tw, tid);

    const float s0    = 2.f * DT_S * (W0_C + sqrtf(2.f + W0_C * W0_C)) / (4.f * PI_F);
    const float s     = s0 * exp2f(0.125f * (float)sidx);
    const float inv_s = 1.f / s;

    const float2* yh1 = spec + (size_t)(b * 2 + 0) * N;
    const float2* yh2 = spec + (size_t)(b * 2 + 1) * N;

    // Morlet filter (w>0 one-sided), unit-energy norm, ifft 1/N folded in.
    // Upper half (k>=1024) is identically zero: skip the loads entirely.
    const float nrm   = PIM14 * sqrtf(TWOPI_F * s / DT_S) * (1.f / N);
    const float wstep = TWOPI_F / ((float)N * DT_S);

    float2 w1[8], w2[8];
    #pragma unroll
    for (int i = 0; i < 4; ++i) {
        int   k = tid + i * NT;
        float f = 0.f;
        if (k >= 1) {
            float arg = s * (wstep * (float)k) - W0_C;
            f = nrm * __expf(-0.5f * arg * arg);
        }
        float2 a = yh1[k];
        float2 c = yh2[k];
        w1[i] = make_float2(a.x * f, a.y * f);
        w2[i] = make_float2(c.x * f, c.y * f);
    }
    #pragma unroll
    for (int i = 4; i < 8; ++i) {
        w1[i] = make_float2(0.f, 0.f);
        w2[i] = make_float2(0.f, 0.f);
    }
    fft2048_dual<+1, true>(w1, w2, U, V, tw, tid);   // W1, W2 in regs (fused pair)

    // pointwise products entirely in registers
    float2 P[8], C[8];
    #pragma unroll
    for (int i = 0; i < 8; ++i) {
        float2 a = w1[i], c = w2[i];
        P[i] = make_float2((a.x * a.x + a.y * a.y) * inv_s,
                           (c.x * c.x + c.y * c.y) * inv_s);
        C[i] = make_float2((a.x * c.x + a.y * c.y) * inv_s,
                           (a.y * c.x - a.x * c.y) * inv_s);
    }

    // Gaussian time-smoothing in Fourier domain (1/N folded into F)
    const float sdt = s / DT_S;
    const float fc  = -0.5f * sdt * sdt * (TWOPI_F / (float)N) * (TWOPI_F / (float)N);

    fft2048_dual<-1, false>(P, C, U, V, tw, tid);    // fused forward pair

    // filter computed once, applied to both P and C
    #pragma unroll
    for (int i = 0; i < 8; ++i) {
        int   k  = tid + i * NT;
        int   mk = min(k, N - k);
        float F  = __expf(fc * (float)(mk * mk)) * (1.f / N);
        P[i].x *= F; P[i].y *= F;
        C[i].x *= F; C[i].y *= F;
    }

    fft2048_dual<+1, false>(P, C, U, V, tw, tid);    // fused inverse pair: Psm, Csm in regs

    u2v* To = T + ((size_t)bl * NSC + sidx) * N;
    #pragma unroll
    for (int i = 0; i < 8; ++i) {
        int k = tid + i * NT;
        // bf16x4 packed, non-temporal: T is stream-once; coherence ratio is
        // quadratic-over-quadratic in T, so bf16's 0.2% rel. error survives.
        ntstore2(&To[k], pack4(P[i].x, P[i].y, C[i].x, C[i].y));
    }
}

// ---------------- K3: scale-axis boxcar + coherence, running-sum version ----
// Window at scale i covers X[i-5..i+4] with half-weight ends /9.
// Running sum S += X[i+4] - X[i-6]; ends X[i-5] (=prev[u+1]) and X[i+4] (=cur[u]).
// Chunks of 10 with two statically-indexed reg arrays whose roles alternate:
// no ring shifts, no 10-wide re-summation (was ~95 VALU/iter -> ~30).
__device__ __forceinline__ void coh_chunk(const u2v* __restrict__ col, int c0, int bEnd,
                                          float4 (&prev)[10], float4 (&cur)[10],
                                          float4& S, float& acc) {
    #pragma unroll
    for (int u = 0; u < 10; ++u) {
        int idx = c0 + 4 + u;
        cur[u] = (idx < NSC) ? unpack4(ntload2(&col[(size_t)idx * N]))
                             : make_float4(0.f, 0.f, 0.f, 0.f);
    }
    const float w9 = 1.f / 9.f;
    #pragma unroll
    for (int u = 0; u < 10; ++u) {
        int i = c0 + u;
        if (i < bEnd) {                       // uniform branch (i is scalar)
            float4 in  = cur[u];
            float4 out = prev[u];
            float4 e0  = (u < 9) ? prev[u + 1] : cur[0];
            S.x += in.x - out.x;  S.y += in.y - out.y;
            S.z += in.z - out.z;  S.w += in.w - out.w;
            float s1 = (S.x - 0.5f * (e0.x + in.x)) * w9;
            float s2 = (S.y - 0.5f * (e0.y + in.y)) * w9;
            float sr = (S.z - 0.5f * (e0.z + in.z)) * w9;
            float si = (S.w - 0.5f * (e0.w + in.w)) * w9;
            acc += (sr * sr + si * si) * __builtin_amdgcn_rcpf(s1 * s2);
        }
    }
}

__global__ __launch_bounds__(NT) void k_coh(const u2v* __restrict__ T,
                                            float* __restrict__ coh, int b0) {
    const int bl   = blockIdx.x >> 4;
    const int r    = blockIdx.x & 15;
    const int tile = r & 7;
    const int g    = r >> 3;
    const int t    = (tile << 8) + threadIdx.x;
    const int b    = b0 + bl;
    const u2v* col = T + (size_t)bl * NSC * N + t;

    const int a    = g * 41;
    const int bEnd = (g == 0) ? 41 : NSC;

    // init: A[u] = X[a-6+u] (state as of iteration a-1), S = sum(A)
    float4 A[10], B[10];
    float4 S = make_float4(0.f, 0.f, 0.f, 0.f);
    #pragma unroll
    for (int u = 0; u < 10; ++u) {
        int j = a - 6 + u;
        A[u] = (j >= 0 && j < NSC) ? unpack4(ntload2(&col[(size_t)j * N]))
                                   : make_float4(0.f, 0.f, 0.f, 0.f);
        S.x += A[u].x; S.y += A[u].y; S.z += A[u].z; S.w += A[u].w;
    }

    float acc = 0.f;
    coh_chunk(col, a +  0, bEnd, A, B, S, acc);
    coh_chunk(col, a + 10, bEnd, B, A, S, acc);
    coh_chunk(col, a + 20, bEnd, A, B, S, acc);
    coh_chunk(col, a + 30, bEnd, B, A, S, acc);
    coh_chunk(col, a + 40, bEnd, A, B, S, acc);   // g=1: fully guarded out

    // partial sum plane g; k_win adds the two planes
    coh[((size_t)g * BATCH + b) * N + t] = acc;
}

// ---------------- K4: sliding-window sum via block-wide cumsum + diff -------
__global__ __launch_bounds__(NT) void k_win(const float* __restrict__ coh,
                                            float* __restrict__ out) {
    __shared__ float cs[N + 1];
    __shared__ float tot[NT];
    const int b   = blockIdx.x;
    const int tid = threadIdx.x;
    const float* r0 = coh + (size_t)b * N;
    const float* r1 = coh + (size_t)(BATCH + b) * N;

    // thread-local chunk [8*tid, 8*tid+8): load both planes, local inclusive scan
    float v[8];
    #pragma unroll
    for (int j = 0; j < 8; ++j) {
        int i = tid * 8 + j;
        v[j] = r0[i] + r1[i];
    }
    #pragma unroll
    for (int j = 1; j < 8; ++j) v[j] += v[j - 1];
    tot[tid] = v[7];
    __syncthreads();
    // Hillis-Steele inclusive scan over the 256 chunk totals
    for (int o = 1; o < NT; o <<= 1) {
        float tv = (tid >= o) ? tot[tid - o] : 0.f;
        __syncthreads();
        tot[tid] += tv;
        __syncthreads();
    }
    const float off = (tid > 0) ? tot[tid - 1] : 0.f;
    if (tid == 0) cs[0] = 0.f;
    #pragma unroll
    for (int j = 0; j < 8; ++j) cs[tid * 8 + j + 1] = off + v[j];
    __syncthreads();
    for (int t0 = tid; t0 < NOUT; t0 += NT)
        out[(size_t)b * NOUT + t0] = cs[t0 + WS_WIN] - cs[t0];
}

// ---------------- host launcher ----------------
extern "C" void kernel_launch(void* const* d_in, const int* in_sizes, int n_in,
                              void* d_out, int out_size, void* d_ws, size_t ws_size,
                              hipStream_t stream) {
    const float* x   = (const float*)d_in[0];
    float*       out = (float*)d_out;
    char*        ws  = (char*)d_ws;

    const size_t spec_bytes = (size_t)BATCH * 2 * N * sizeof(float2); // 2 MB
    const size_t coh_bytes  = (size_t)2 * BATCH * N * sizeof(float);  // 1 MB (2 planes)
    const size_t perBatchT  = (size_t)NSC * N * sizeof(u2v);          // ~1.33 MB (bf16x4)

    float2* spec = (float2*)ws;
    float*  coh  = (float*)(ws + spec_bytes);
    u2v*    T    = (u2v*)(ws + spec_bytes + coh_bytes);

    size_t avail = (ws_size > spec_bytes + coh_bytes) ? (ws_size - spec_bytes - coh_bytes) : 0;
    int chunk = (int)(avail / perBatchT);
    if (chunk < 1) chunk = 1;
    if (chunk > BATCH) chunk = BATCH;

    k_fft_in<<<BATCH * 2, NT, 0, stream>>>(x, spec);
    for (int b0 = 0; b0 < BATCH; b0 += chunk) {
        int cb = BATCH - b0 < chunk ? BATCH - b0 : chunk;
        k_wct<<<cb * NSC, NT, 0, stream>>>(spec, T, b0);
        k_coh<<<cb * 16, NT, 0, stream>>>(T, coh, b0);
    }
    k_win<<<BATCH, NT, 0, stream>>>(coh, out);
}